// Round 1
// baseline (263.507 us; speedup 1.0000x reference)
//
#include <hip/hip_runtime.h>
#include <hip/hip_bf16.h>

#define HW_ 36864
#define W_ 192
#define H_ 192
#define NPIX_ 73728
#define TWO_PI_F 6.283185307179586f

typedef __attribute__((ext_vector_type(8))) short bfrag;
typedef __attribute__((ext_vector_type(4))) float f4;

__device__ __constant__ float DT_G[12] = {
    1.0f, 2.154434690031884f, 4.641588833612779f, 10.0f,
    21.54434690031884f, 46.41588833612779f, 100.0f, 215.4434690031884f,
    464.1588833612779f, 1000.0f, 2154.434690031884f, 4641.588833612779f};

__device__ __forceinline__ unsigned short f2bf(float f) {
    __hip_bfloat16 h = __float2bfloat16(f);
    unsigned short u;
    __builtin_memcpy(&u, &h, 2);
    return u;
}

struct __align__(16) Smem {
    unsigned short A[10 * 1024]; // frag-order A tiles: [0..1]=xin (32 rows), [2..9]=wrp (128 rows)
    float wl[864];               // conv weights
    float pbl[192];              // window position bias [v][c]
    float offs[32];              // per-pixel offsets
    float cpart[8][32];          // conv partial sums [chan-group][pixel]
}; // 25856 B -> 6 blocks/CU (was 41984 -> 3)

// A-frag storage index (u16 units) for (row m in tile, k in 0..63)
__device__ __forceinline__ int a_idx(int tile, int m, int k) {
    return tile * 1024 + ((k >> 5) << 9) + (m << 3) + (((k >> 3) & 3) << 7) + (k & 7);
}

// B fragment straight from global f32 weights w[k][128]; k>=48 -> 0
__device__ __forceinline__ bfrag loadB(const float* __restrict__ w, int h, int ks,
                                       int lq, int lg) {
    int n = (h << 4) + lq;
    int k0 = (ks << 5) + (lg << 3);
    bfrag r;
#pragma unroll
    for (int j = 0; j < 8; ++j) {
        int k = k0 + j;
        float f = (k < 48) ? w[k * 128 + n] : 0.0f;
        r[j] = (short)f2bf(f);
    }
    return r;
}

__global__ __launch_bounds__(256, 4) void fused_kernel(
    const float* __restrict__ y, const float* __restrict__ x,
    const float* __restrict__ cw, const float* __restrict__ cb,
    const float* __restrict__ qw, const float* __restrict__ qb,
    const float* __restrict__ kw, const float* __restrict__ kb,
    const float* __restrict__ vw, const float* __restrict__ vb,
    float* __restrict__ out) {
    __shared__ Smem sm;
    int tid = threadIdx.x;
    int pix0 = blockIdx.x * 32;
    int n = pix0 / HW_;
    int rem0 = pix0 - n * HW_;
    // W_ % 32 == 0: all 32 pixels of a block share one image row
    int row0 = rem0 / W_;
    int col0 = rem0 - row0 * W_;

    // ---- phase 1: conv weights, position bias, zero A ----
    for (int i = tid; i < 864; i += 256) sm.wl[i] = cw[i];
    if (tid < 192) {
        int v = tid / 48, c = tid - (tid / 48) * 48;
        int iy = v >> 1, ix = v & 1;
        int cc = (c < 24) ? c : c - 24;
        int sel = (c < 24) ? iy : ix;
        float e = sel ? (TWO_PI_F / (1.0f + 1e-6f)) : 0.0f;
        int j = cc >> 1;
        float arg = e / DT_G[j];
        sm.pbl[v * 48 + c] = (cc & 1) ? __cosf(arg) : __sinf(arg);
    }
    for (int i = tid; i < 5120; i += 256) ((unsigned int*)sm.A)[i] = 0u;
    __syncthreads();

    // ---- phase 2: 3x3 conv -> offs[32], lane<->pixel mapping for coalescing ----
    {
        int p = tid & 31;    // pixel (consecutive lanes -> consecutive cols)
        int sub = tid >> 5;  // channel group 0..7
        int col = col0 + p;
        float acc = 0.0f;
#pragma unroll 4
        for (int icl = 0; icl < 12; ++icl) {
            int ic = sub * 12 + icl;
            const float* src = (ic < 48) ? y : x;
            int c = (ic < 48) ? ic : ic - 48;
            size_t base = (size_t)(n * 48 + c) * HW_;
#pragma unroll
            for (int ky = 0; ky < 3; ++ky) {
                int r = row0 + ky - 1;
                if ((unsigned)r < (unsigned)H_) {
                    const float* rp = src + base + (size_t)r * W_;
#pragma unroll
                    for (int kx = 0; kx < 3; ++kx) {
                        int ccx = col + kx - 1;
                        if ((unsigned)ccx < (unsigned)W_)
                            acc += rp[ccx] * sm.wl[ic * 9 + ky * 3 + kx];
                    }
                }
            }
        }
        sm.cpart[sub][p] = acc;
    }
    __syncthreads();
    if (tid < 32) {
        float a = sm.cpart[0][tid];
#pragma unroll
        for (int s2 = 1; s2 < 8; ++s2) a += sm.cpart[s2][tid];
        sm.offs[tid] = (a + cb[0]) * (2.0f / (float)W_);
    }
    __syncthreads();

    // ---- phase 3: stage A operands (bf16, frag order) ----
    // xin: 32px x 48c  (x + point-PE)
    for (int e = tid; e < 1536; e += 256) {
        int c = e >> 5, p = e & 31;
        int rem = rem0 + p;
        float o = sm.offs[p];
        float gx = (float)(col0 + p) + o;
        float fr = gx - floorf(gx);
        float pe;
        if (c < 24) {
            pe = (c & 1) ? 1.0f : 0.0f; // frac_y == 0
        } else {
            int cc = c - 24;
            int j = cc >> 1;
            float t1 = fr / (2.0f + 1e-6f);
            float arg = (t1 * TWO_PI_F) / DT_G[j];
            pe = (cc & 1) ? __cosf(arg) : __sinf(arg);
        }
        float val = x[(size_t)(n * 48 + c) * HW_ + rem] + pe;
        sm.A[a_idx(p >> 4, p & 15, c)] = f2bf(val);
    }
    // wrp: 128 rows (px*4+v) x 48c  (gathered y + window bias)
    for (int e = tid; e < 6144; e += 256) {
        int c = e >> 7, r = e & 127;
        int p = r >> 2, v = r & 3;
        float o = sm.offs[p];
        float gx = (float)(col0 + p) + o;
        float fx = floorf(gx);
        int dy = v >> 1, dx = v & 1;
        int rr = (int)fminf(fmaxf((float)(row0 + dy), 0.0f), 191.0f);
        int ccx = (int)fminf(fmaxf(fx + (float)dx, 0.0f), 191.0f);
        float val = y[(size_t)(n * 48 + c) * HW_ + rr * W_ + ccx] + sm.pbl[v * 48 + c];
        sm.A[a_idx(2 + (r >> 4), r & 15, c)] = f2bf(val);
    }
    __syncthreads();

    // ---- phase 4: MFMA projections + register attention + direct global store ----
    int lane = tid & 63, wid = tid >> 6;
    int lq = lane & 15, lg = lane >> 4;

    bfrag qA[2][2], wA[8][2];
#pragma unroll
    for (int t = 0; t < 2; ++t)
#pragma unroll
        for (int ks = 0; ks < 2; ++ks)
            qA[t][ks] = *(const bfrag*)&sm.A[t * 1024 + ks * 512 + lane * 8];
#pragma unroll
    for (int t = 0; t < 8; ++t)
#pragma unroll
        for (int ks = 0; ks < 2; ++ks)
            wA[t][ks] = *(const bfrag*)&sm.A[(2 + t) * 1024 + ks * 512 + lane * 8];

#pragma unroll
    for (int hh = 0; hh < 2; ++hh) {
        int h = wid * 2 + hh;
        float qbv = qb[(h << 4) + lq];
        float kbv = kb[(h << 4) + lq];
        float vbv = vb[(h << 4) + lq];

        bfrag qB0 = loadB(qw, h, 0, lq, lg), qB1 = loadB(qw, h, 1, lq, lg);
        f4 qacc[2];
#pragma unroll
        for (int t = 0; t < 2; ++t) {
            f4 a = {qbv, qbv, qbv, qbv};
            a = __builtin_amdgcn_mfma_f32_16x16x32_bf16(qA[t][0], qB0, a, 0, 0, 0);
            a = __builtin_amdgcn_mfma_f32_16x16x32_bf16(qA[t][1], qB1, a, 0, 0, 0);
            qacc[t] = a;
        }
        bfrag kB0 = loadB(kw, h, 0, lq, lg), kB1 = loadB(kw, h, 1, lq, lg);
        bfrag vB0 = loadB(vw, h, 0, lq, lg), vB1 = loadB(vw, h, 1, lq, lg);

        float* obase = out + (size_t)(n * 128 + (h << 4) + lq) * HW_ + rem0;

#pragma unroll
        for (int m = 0; m < 8; ++m) {
            f4 ka = {kbv, kbv, kbv, kbv};
            ka = __builtin_amdgcn_mfma_f32_16x16x32_bf16(wA[m][0], kB0, ka, 0, 0, 0);
            ka = __builtin_amdgcn_mfma_f32_16x16x32_bf16(wA[m][1], kB1, ka, 0, 0, 0);
            f4 va = {vbv, vbv, vbv, vbv};
            va = __builtin_amdgcn_mfma_f32_16x16x32_bf16(wA[m][0], vB0, va, 0, 0, 0);
            va = __builtin_amdgcn_mfma_f32_16x16x32_bf16(wA[m][1], vB1, va, 0, 0, 0);

            // q broadcast: pixel p = 4m+lg lives in qacc[m>>2], reg lg, lane (m&3)*16+lq
            int src = ((m & 3) << 4) | lq;
            f4 qa = qacc[m >> 2];
            float t0 = __shfl(qa.x, src), t1 = __shfl(qa.y, src);
            float t2 = __shfl(qa.z, src), t3 = __shfl(qa.w, src);
            float qv = (lg == 0) ? t0 : (lg == 1) ? t1 : (lg == 2) ? t2 : t3;
            qv *= 0.25f; // HEAD_DIM^-0.5

            float s0 = qv * ka.x, s1 = qv * ka.y, s2 = qv * ka.z, s3 = qv * ka.w;
#pragma unroll
            for (int msk = 1; msk < 16; msk <<= 1) {
                s0 += __shfl_xor(s0, msk);
                s1 += __shfl_xor(s1, msk);
                s2 += __shfl_xor(s2, msk);
                s3 += __shfl_xor(s3, msk);
            }
            float mx = fmaxf(fmaxf(s0, s1), fmaxf(s2, s3));
            float e0 = __expf(s0 - mx), e1 = __expf(s1 - mx);
            float e2 = __expf(s2 - mx), e3 = __expf(s3 - mx);
            float rden = 1.0f / (e0 + e1 + e2 + e3);
            float o = (e0 * va.x + e1 * va.y + e2 * va.z + e3 * va.w) * rden;
            // direct store: 16 channels x 16B segments per wave-store; the 8 m-iters
            // of a wave fill each 128B line -> L2 write-combines to full lines
            obase[(m << 2) + lg] = o;
        }
    }
}

extern "C" void kernel_launch(void* const* d_in, const int* in_sizes, int n_in,
                              void* d_out, int out_size, void* d_ws, size_t ws_size,
                              hipStream_t stream) {
    hipLaunchKernelGGL(fused_kernel, dim3(NPIX_ / 32), dim3(256), 0, stream,
                       (const float*)d_in[0], (const float*)d_in[1],
                       (const float*)d_in[2], (const float*)d_in[3],
                       (const float*)d_in[4], (const float*)d_in[5],
                       (const float*)d_in[6], (const float*)d_in[7],
                       (const float*)d_in[8], (const float*)d_in[9],
                       (float*)d_out);
}

// Round 2
// 236.892 us; speedup vs baseline: 1.1124x; 1.1124x over previous
//
#include <hip/hip_runtime.h>
#include <hip/hip_bf16.h>

#define HW_ 36864
#define W_ 192
#define H_ 192
#define NPIX_ 73728
#define TWO_PI_F 6.283185307179586f

typedef __attribute__((ext_vector_type(8))) short bfrag;
typedef __attribute__((ext_vector_type(4))) float f4;

__device__ __constant__ float DT_G[12] = {
    1.0f, 2.154434690031884f, 4.641588833612779f, 10.0f,
    21.54434690031884f, 46.41588833612779f, 100.0f, 215.4434690031884f,
    464.1588833612779f, 1000.0f, 2154.434690031884f, 4641.588833612779f};

__device__ __forceinline__ unsigned short f2bf(float f) {
    __hip_bfloat16 h = __float2bfloat16(f);
    unsigned short u;
    __builtin_memcpy(&u, &h, 2);
    return u;
}

struct __align__(16) Smem {
    unsigned short A[10 * 1024]; // frag-order A tiles: [0..1]=xin (32 rows), [2..9]=wrp (128 rows)
    float outt[128 * 33];        // out tile [ch][32px], pad 33 (full-line flush)
    float wl[864];               // conv weights
    float pbl[192];              // window position bias [v][c]
    float offs[32];              // per-pixel offsets
    float cpart[8][32];          // conv partial sums [chan-group][pixel]
}; // ~42.8 KB -> 3 blocks/CU (round-1 showed residency insensitive to LDS)

// A-frag storage index (u16 units) for (row m in tile, k in 0..63)
__device__ __forceinline__ int a_idx(int tile, int m, int k) {
    return tile * 1024 + ((k >> 5) << 9) + (m << 3) + (((k >> 3) & 3) << 7) + (k & 7);
}

// ---- prep kernel: build frag-ordered bf16 weights once into workspace ----
// layout: [mat 0..2][h 0..7][ks 0..1][lane 0..63][j 0..7] bf16  (24576 elems, 48 KB)
__global__ void prep_wfrag(const float* __restrict__ qw, const float* __restrict__ kw,
                           const float* __restrict__ vw, unsigned short* __restrict__ wsb) {
    int idx = blockIdx.x * 256 + threadIdx.x;
    if (idx >= 24576) return;
    int j = idx & 7;
    int lane = (idx >> 3) & 63;
    int ks = (idx >> 9) & 1;
    int h = (idx >> 10) & 7;
    int mat = idx >> 13;
    const float* w = (mat == 0) ? qw : (mat == 1) ? kw : vw;
    int k = ks * 32 + ((lane >> 4) << 3) + j;
    int n = (h << 4) + (lane & 15);
    float f = (k < 48) ? w[k * 128 + n] : 0.0f;
    wsb[idx] = f2bf(f);
}

__global__ __launch_bounds__(256, 3) void fused_kernel(
    const float* __restrict__ y, const float* __restrict__ x,
    const float* __restrict__ cw, const float* __restrict__ cb,
    const float* __restrict__ qb, const float* __restrict__ kb,
    const float* __restrict__ vb, const unsigned short* __restrict__ wsb,
    float* __restrict__ out) {
    __shared__ Smem sm;
    int tid = threadIdx.x;
    int pix0 = blockIdx.x * 32;
    int n = pix0 / HW_;
    int rem0 = pix0 - n * HW_;
    // W_ % 32 == 0: all 32 pixels of a block share one image row
    int row0 = rem0 / W_;
    int col0 = rem0 - row0 * W_;

    // ---- phase 1: conv weights, position bias, zero A ----
    for (int i = tid; i < 864; i += 256) sm.wl[i] = cw[i];
    if (tid < 192) {
        int v = tid / 48, c = tid - (tid / 48) * 48;
        int iy = v >> 1, ix = v & 1;
        int cc = (c < 24) ? c : c - 24;
        int sel = (c < 24) ? iy : ix;
        float e = sel ? (TWO_PI_F / (1.0f + 1e-6f)) : 0.0f;
        int j = cc >> 1;
        float arg = e / DT_G[j];
        sm.pbl[v * 48 + c] = (cc & 1) ? __cosf(arg) : __sinf(arg);
    }
    for (int i = tid; i < 5120; i += 256) ((unsigned int*)sm.A)[i] = 0u;
    __syncthreads();

    // ---- phase 2: 3x3 conv -> offs[32], lane<->pixel mapping for coalescing ----
    {
        int p = tid & 31;    // pixel (consecutive lanes -> consecutive cols)
        int sub = tid >> 5;  // channel group 0..7
        int col = col0 + p;
        float acc = 0.0f;
#pragma unroll 4
        for (int icl = 0; icl < 12; ++icl) {
            int ic = sub * 12 + icl;
            const float* src = (ic < 48) ? y : x;
            int c = (ic < 48) ? ic : ic - 48;
            size_t base = (size_t)(n * 48 + c) * HW_;
#pragma unroll
            for (int ky = 0; ky < 3; ++ky) {
                int r = row0 + ky - 1;
                if ((unsigned)r < (unsigned)H_) {
                    const float* rp = src + base + (size_t)r * W_;
#pragma unroll
                    for (int kx = 0; kx < 3; ++kx) {
                        int ccx = col + kx - 1;
                        if ((unsigned)ccx < (unsigned)W_)
                            acc += rp[ccx] * sm.wl[ic * 9 + ky * 3 + kx];
                    }
                }
            }
        }
        sm.cpart[sub][p] = acc;
    }
    __syncthreads();
    if (tid < 32) {
        float a = sm.cpart[0][tid];
#pragma unroll
        for (int s2 = 1; s2 < 8; ++s2) a += sm.cpart[s2][tid];
        sm.offs[tid] = (a + cb[0]) * (2.0f / (float)W_);
    }
    __syncthreads();

    // ---- phase 3: stage A operands (bf16, frag order) ----
    // xin: 32px x 48c  (x + point-PE)
    for (int e = tid; e < 1536; e += 256) {
        int c = e >> 5, p = e & 31;
        int rem = rem0 + p;
        float o = sm.offs[p];
        float gx = (float)(col0 + p) + o;
        float fr = gx - floorf(gx);
        float pe;
        if (c < 24) {
            pe = (c & 1) ? 1.0f : 0.0f; // frac_y == 0
        } else {
            int cc = c - 24;
            int j = cc >> 1;
            float t1 = fr / (2.0f + 1e-6f);
            float arg = (t1 * TWO_PI_F) / DT_G[j];
            pe = (cc & 1) ? __cosf(arg) : __sinf(arg);
        }
        float val = x[(size_t)(n * 48 + c) * HW_ + rem] + pe;
        sm.A[a_idx(p >> 4, p & 15, c)] = f2bf(val);
    }
    // wrp: 128 rows (px*4+v) x 48c  (gathered y + window bias)
    for (int e = tid; e < 6144; e += 256) {
        int c = e >> 7, r = e & 127;
        int p = r >> 2, v = r & 3;
        float o = sm.offs[p];
        float gx = (float)(col0 + p) + o;
        float fx = floorf(gx);
        int dy = v >> 1, dx = v & 1;
        int rr = (int)fminf(fmaxf((float)(row0 + dy), 0.0f), 191.0f);
        int ccx = (int)fminf(fmaxf(fx + (float)dx, 0.0f), 191.0f);
        float val = y[(size_t)(n * 48 + c) * HW_ + rr * W_ + ccx] + sm.pbl[v * 48 + c];
        sm.A[a_idx(2 + (r >> 4), r & 15, c)] = f2bf(val);
    }
    __syncthreads();

    // ---- phase 4: MFMA projections + register attention ----
    int lane = tid & 63, wid = tid >> 6;
    int lq = lane & 15, lg = lane >> 4;

    bfrag qA[2][2], wA[8][2];
#pragma unroll
    for (int t = 0; t < 2; ++t)
#pragma unroll
        for (int ks = 0; ks < 2; ++ks)
            qA[t][ks] = *(const bfrag*)&sm.A[t * 1024 + ks * 512 + lane * 8];
#pragma unroll
    for (int t = 0; t < 8; ++t)
#pragma unroll
        for (int ks = 0; ks < 2; ++ks)
            wA[t][ks] = *(const bfrag*)&sm.A[(2 + t) * 1024 + ks * 512 + lane * 8];

#pragma unroll
    for (int hh = 0; hh < 2; ++hh) {
        int h = wid * 2 + hh;
        float qbv = qb[(h << 4) + lq];
        float kbv = kb[(h << 4) + lq];
        float vbv = vb[(h << 4) + lq];

        // precomputed frag-order weights: coalesced b128 loads, L2-resident
        const int hb = ((h << 1)) * 64 + lane; // (h*2+ks)*64+lane, ks=0
        bfrag qB0 = *(const bfrag*)&wsb[(0 * 1024 + hb) * 8];
        bfrag qB1 = *(const bfrag*)&wsb[(0 * 1024 + hb + 64) * 8];
        bfrag kB0 = *(const bfrag*)&wsb[(1 * 1024 + hb) * 8];
        bfrag kB1 = *(const bfrag*)&wsb[(1 * 1024 + hb + 64) * 8];
        bfrag vB0 = *(const bfrag*)&wsb[(2 * 1024 + hb) * 8];
        bfrag vB1 = *(const bfrag*)&wsb[(2 * 1024 + hb + 64) * 8];

        f4 qacc[2];
#pragma unroll
        for (int t = 0; t < 2; ++t) {
            f4 a = {qbv, qbv, qbv, qbv};
            a = __builtin_amdgcn_mfma_f32_16x16x32_bf16(qA[t][0], qB0, a, 0, 0, 0);
            a = __builtin_amdgcn_mfma_f32_16x16x32_bf16(qA[t][1], qB1, a, 0, 0, 0);
            qacc[t] = a;
        }

#pragma unroll
        for (int m = 0; m < 8; ++m) {
            f4 ka = {kbv, kbv, kbv, kbv};
            ka = __builtin_amdgcn_mfma_f32_16x16x32_bf16(wA[m][0], kB0, ka, 0, 0, 0);
            ka = __builtin_amdgcn_mfma_f32_16x16x32_bf16(wA[m][1], kB1, ka, 0, 0, 0);
            f4 va = {vbv, vbv, vbv, vbv};
            va = __builtin_amdgcn_mfma_f32_16x16x32_bf16(wA[m][0], vB0, va, 0, 0, 0);
            va = __builtin_amdgcn_mfma_f32_16x16x32_bf16(wA[m][1], vB1, va, 0, 0, 0);

            // q broadcast: pixel p = 4m+lg lives in qacc[m>>2], reg lg, lane (m&3)*16+lq
            int src = ((m & 3) << 4) | lq;
            f4 qa = qacc[m >> 2];
            float t0 = __shfl(qa.x, src), t1 = __shfl(qa.y, src);
            float t2 = __shfl(qa.z, src), t3 = __shfl(qa.w, src);
            float qv = (lg == 0) ? t0 : (lg == 1) ? t1 : (lg == 2) ? t2 : t3;
            qv *= 0.25f; // HEAD_DIM^-0.5

            float s0 = qv * ka.x, s1 = qv * ka.y, s2 = qv * ka.z, s3 = qv * ka.w;
#pragma unroll
            for (int msk = 1; msk < 16; msk <<= 1) {
                s0 += __shfl_xor(s0, msk);
                s1 += __shfl_xor(s1, msk);
                s2 += __shfl_xor(s2, msk);
                s3 += __shfl_xor(s3, msk);
            }
            float mx = fmaxf(fmaxf(s0, s1), fmaxf(s2, s3));
            float e0 = __expf(s0 - mx), e1 = __expf(s1 - mx);
            float e2 = __expf(s2 - mx), e3 = __expf(s3 - mx);
            float rden = 1.0f / (e0 + e1 + e2 + e3);
            float o = (e0 * va.x + e1 * va.y + e2 * va.z + e3 * va.w) * rden;
            sm.outt[((h << 4) + lq) * 33 + (m << 2) + lg] = o;
        }
    }
    __syncthreads();

    // ---- phase 5: coalesced flush (64B lines per channel-half) ----
    {
        int ch = tid >> 1, half = tid & 1;
        const float* sp = &sm.outt[ch * 33 + half * 16];
        float4* dst = (float4*)(out + (size_t)(n * 128 + ch) * HW_ + rem0 + half * 16);
#pragma unroll
        for (int i = 0; i < 4; ++i)
            dst[i] = make_float4(sp[4 * i], sp[4 * i + 1], sp[4 * i + 2], sp[4 * i + 3]);
    }
}

extern "C" void kernel_launch(void* const* d_in, const int* in_sizes, int n_in,
                              void* d_out, int out_size, void* d_ws, size_t ws_size,
                              hipStream_t stream) {
    unsigned short* wsb = (unsigned short*)d_ws;
    hipLaunchKernelGGL(prep_wfrag, dim3(96), dim3(256), 0, stream,
                       (const float*)d_in[4], (const float*)d_in[6],
                       (const float*)d_in[8], wsb);
    hipLaunchKernelGGL(fused_kernel, dim3(NPIX_ / 32), dim3(256), 0, stream,
                       (const float*)d_in[0], (const float*)d_in[1],
                       (const float*)d_in[2], (const float*)d_in[3],
                       (const float*)d_in[5], (const float*)d_in[7],
                       (const float*)d_in[9], wsb,
                       (float*)d_out);
}

// Round 3
// 182.074 us; speedup vs baseline: 1.4473x; 1.3011x over previous
//
#include <hip/hip_runtime.h>
#include <hip/hip_bf16.h>

#define HW_ 36864
#define W_ 192
#define H_ 192
#define NPIX_ 73728
#define TWO_PI_F 6.283185307179586f

typedef __attribute__((ext_vector_type(8))) short bfrag;
typedef __attribute__((ext_vector_type(4))) float f4;

__device__ __constant__ float DT_G[12] = {
    1.0f, 2.154434690031884f, 4.641588833612779f, 10.0f,
    21.54434690031884f, 46.41588833612779f, 100.0f, 215.4434690031884f,
    464.1588833612779f, 1000.0f, 2154.434690031884f, 4641.588833612779f};

__device__ __forceinline__ unsigned short f2bf(float f) {
    __hip_bfloat16 h = __float2bfloat16(f);
    unsigned short u;
    __builtin_memcpy(&u, &h, 2);
    return u;
}

// A-frag storage index (u16 units) for (row m in tile, k in 0..63)
__device__ __forceinline__ int a_idx(int tile, int m, int k) {
    return tile * 1024 + ((k >> 5) << 9) + (m << 3) + (((k >> 3) & 3) << 7) + (k & 7);
}

// ---- prep kernel: build frag-ordered bf16 weights once into workspace ----
// layout: [mat 0..2][h 0..7][ks 0..1][lane 0..63][j 0..7] bf16  (24576 elems, 48 KB)
__global__ void prep_wfrag(const float* __restrict__ qw, const float* __restrict__ kw,
                           const float* __restrict__ vw, unsigned short* __restrict__ wsb) {
    int idx = blockIdx.x * 256 + threadIdx.x;
    if (idx >= 24576) return;
    int j = idx & 7;
    int lane = (idx >> 3) & 63;
    int ks = (idx >> 9) & 1;
    int h = (idx >> 10) & 7;
    int mat = idx >> 13;
    const float* w = (mat == 0) ? qw : (mat == 1) ? kw : vw;
    int k = ks * 32 + ((lane >> 4) << 3) + j;
    int n = (h << 4) + (lane & 15);
    float f = (k < 48) ? w[k * 128 + n] : 0.0f;
    wsb[idx] = f2bf(f);
}

// ---- conv kernel: 3x3 conv -> per-pixel offset, branch-free batched loads ----
// grid 1152 blocks (64 px each), 4 waves = 4 channel-groups of 24; same 8x12
// summation grouping as the fused version for numerical stability.
__global__ __launch_bounds__(256, 4) void conv_kernel(
    const float* __restrict__ y, const float* __restrict__ x,
    const float* __restrict__ cw, const float* __restrict__ cb,
    float* __restrict__ offs_g) {
    __shared__ float part[8][64];
    int tid = threadIdx.x;
    int bid = blockIdx.x;
    int b = (bid & 7) * 144 + (bid >> 3); // bijective XCD swizzle (1152 = 8*144)
    int pix0 = b * 64;
    int n = pix0 / HW_;
    int rem = pix0 - n * HW_;
    int row0 = rem / W_;
    int col0 = rem - row0 * W_; // 64 px share one row (W_%64==0)
    int lane = tid & 63, w = tid >> 6;
    int col = col0 + lane;

    float m_lf = (col > 0) ? 1.f : 0.f, m_rt = (col < W_ - 1) ? 1.f : 0.f;
    float m_up = (row0 > 0) ? 1.f : 0.f, m_dn = (row0 < H_ - 1) ? 1.f : 0.f;
    int c_lf = col - (col > 0 ? 1 : 0);
    int c_rt = col + (col < W_ - 1 ? 1 : 0);
    int r_up = row0 - (row0 > 0 ? 1 : 0);
    int r_dn = row0 + (row0 < H_ - 1 ? 1 : 0);
    float k0 = m_up * m_lf, k1 = m_up, k2 = m_up * m_rt;
    float k3 = m_lf, k5 = m_rt;
    float k6 = m_dn * m_lf, k7 = m_dn, k8 = m_dn * m_rt;

    auto convch = [&](int ic, float& acc) {
        const float* src = (ic < 48) ? y : x;
        int c = (ic < 48) ? ic : ic - 48;
        const float* b0 = src + (size_t)(n * 48 + c) * HW_;
        const float* pu = b0 + (size_t)r_up * W_;
        const float* pm = b0 + (size_t)row0 * W_;
        const float* pd = b0 + (size_t)r_dn * W_;
        const float* wp = cw + ic * 9;
        acc += pu[c_lf] * (wp[0] * k0);
        acc += pu[col] * (wp[1] * k1);
        acc += pu[c_rt] * (wp[2] * k2);
        acc += pm[c_lf] * (wp[3] * k3);
        acc += pm[col] * wp[4];
        acc += pm[c_rt] * (wp[5] * k5);
        acc += pd[c_lf] * (wp[6] * k6);
        acc += pd[col] * (wp[7] * k7);
        acc += pd[c_rt] * (wp[8] * k8);
    };

    float accA = 0.f, accB = 0.f;
#pragma unroll 4
    for (int icl = 0; icl < 12; ++icl) convch(w * 24 + icl, accA);
#pragma unroll 4
    for (int icl = 12; icl < 24; ++icl) convch(w * 24 + icl, accB);
    part[2 * w][lane] = accA;
    part[2 * w + 1][lane] = accB;
    __syncthreads();
    if (tid < 64) {
        float a = part[0][tid];
#pragma unroll
        for (int s = 1; s < 8; ++s) a += part[s][tid];
        offs_g[pix0 + tid] = (a + cb[0]) * (2.0f / (float)W_);
    }
}

// ---- main kernel ----
struct __align__(16) Smem {
    unsigned short A[10 * 1024]; // [0..1]=xin (32 rows), [2..9]=wrp (128 rows)
    float outt[64 * 33];         // half-pass out tile [64 ch][32px], pad 33
    float pbl[192];              // window position bias [v][c]
    float offs[32];              // per-pixel offsets
}; // ~29.9 KB -> 5 blocks/CU

__global__ __launch_bounds__(256, 5) void fused_kernel(
    const float* __restrict__ y, const float* __restrict__ x,
    const float* __restrict__ qb, const float* __restrict__ kb,
    const float* __restrict__ vb, const unsigned short* __restrict__ wsb,
    const float* __restrict__ offs_g, float* __restrict__ out) {
    __shared__ Smem sm;
    int tid = threadIdx.x;
    int bid = blockIdx.x;
    int b = (bid & 7) * 288 + (bid >> 3); // bijective XCD swizzle (2304 = 8*288)
    int pix0 = b * 32;
    int n = pix0 / HW_;
    int rem0 = pix0 - n * HW_;
    int row0 = rem0 / W_;
    int col0 = rem0 - row0 * W_;

    // xin global prefetch (addresses independent of offs) — hides HBM latency
    float xv[6];
    {
        int p = tid & 31, c0 = tid >> 5;
        const float* xb = x + (size_t)(n * 48) * HW_ + rem0 + p;
#pragma unroll
        for (int k2 = 0; k2 < 6; ++k2) xv[k2] = xb[(size_t)(c0 + 8 * k2) * HW_];
    }

    // ---- phase 1: offs load, position bias, zero A k-pad ----
    if (tid < 32) sm.offs[tid] = offs_g[pix0 + tid];
    if (tid < 192) {
        int v = tid / 48, c = tid - (tid / 48) * 48;
        int iy = v >> 1, ix = v & 1;
        int cc = (c < 24) ? c : c - 24;
        int sel = (c < 24) ? iy : ix;
        float e = sel ? (TWO_PI_F / (1.0f + 1e-6f)) : 0.0f;
        int j = cc >> 1;
        float arg = e / DT_G[j];
        sm.pbl[v * 48 + c] = (cc & 1) ? __cosf(arg) : __sinf(arg);
    }
    // only k in [48,64) slots need zeroing (B is zero there; avoid NaN garbage)
    for (int i = tid; i < 1280; i += 256) {
        int t = i >> 7;
        ((unsigned int*)sm.A)[t * 512 + 384 + (i & 127)] = 0u;
    }
    __syncthreads();

    // ---- phase 2: stage A operands (batched loads -> regs -> bf16 LDS) ----
    // xin: 32px x 48c
    {
        int p = tid & 31, c0 = tid >> 5;
        float o = sm.offs[p];
        float gx = (float)(col0 + p) + o;
        float fr = gx - floorf(gx);
        float t1 = fr / (2.0f + 1e-6f);
#pragma unroll
        for (int k2 = 0; k2 < 6; ++k2) {
            int c = c0 + 8 * k2;
            float pe;
            if (k2 < 3) {
                pe = (c & 1) ? 1.0f : 0.0f; // frac_y == 0
            } else {
                int cc = c - 24;
                float arg = (t1 * TWO_PI_F) / DT_G[cc >> 1];
                pe = (cc & 1) ? __cosf(arg) : __sinf(arg);
            }
            sm.A[a_idx(p >> 4, p & 15, c)] = f2bf(xv[k2] + pe);
        }
    }
    // wrp: 128 rows (px*4+v) x 48c — address calc hoisted, 24 loads batched
    {
        int r = tid & 127, cH = tid >> 7;
        int p = r >> 2, v = r & 3;
        float o = sm.offs[p];
        float gx = (float)(col0 + p) + o;
        float fx = floorf(gx);
        int dy = v >> 1, dx = v & 1;
        int rr = (int)fminf(fmaxf((float)(row0 + dy), 0.0f), 191.0f);
        int ccx = (int)fminf(fmaxf(fx + (float)dx, 0.0f), 191.0f);
        const float* yb = y + (size_t)(n * 48 + cH) * HW_ + rr * W_ + ccx;
        float yv[24];
#pragma unroll
        for (int k2 = 0; k2 < 24; ++k2) yv[k2] = yb[(size_t)(2 * k2) * HW_];
        int t = 2 + (r >> 4), m = r & 15;
#pragma unroll
        for (int k2 = 0; k2 < 24; ++k2) {
            int c = cH + 2 * k2;
            sm.A[a_idx(t, m, c)] = f2bf(yv[k2] + sm.pbl[v * 48 + c]);
        }
    }
    __syncthreads();

    // ---- phase 3: MFMA projections + register attention, per-hh flush ----
    int lane = tid & 63, wid = tid >> 6;
    int lq = lane & 15, lg = lane >> 4;

#pragma unroll
    for (int hh = 0; hh < 2; ++hh) {
        int h = wid * 2 + hh;
        float qbv = qb[(h << 4) + lq];
        float kbv = kb[(h << 4) + lq];
        float vbv = vb[(h << 4) + lq];

        const int hb = (h << 1) * 64 + lane;
        bfrag qB0 = *(const bfrag*)&wsb[(0 * 1024 + hb) * 8];
        bfrag qB1 = *(const bfrag*)&wsb[(0 * 1024 + hb + 64) * 8];
        bfrag kB0 = *(const bfrag*)&wsb[(1 * 1024 + hb) * 8];
        bfrag kB1 = *(const bfrag*)&wsb[(1 * 1024 + hb + 64) * 8];
        bfrag vB0 = *(const bfrag*)&wsb[(2 * 1024 + hb) * 8];
        bfrag vB1 = *(const bfrag*)&wsb[(2 * 1024 + hb + 64) * 8];

        f4 qacc[2];
#pragma unroll
        for (int t = 0; t < 2; ++t) {
            bfrag a0 = *(const bfrag*)&sm.A[t * 1024 + lane * 8];
            bfrag a1 = *(const bfrag*)&sm.A[t * 1024 + 512 + lane * 8];
            f4 a = {qbv, qbv, qbv, qbv};
            a = __builtin_amdgcn_mfma_f32_16x16x32_bf16(a0, qB0, a, 0, 0, 0);
            a = __builtin_amdgcn_mfma_f32_16x16x32_bf16(a1, qB1, a, 0, 0, 0);
            qacc[t] = a;
        }

#pragma unroll
        for (int m = 0; m < 8; ++m) {
            bfrag a0 = *(const bfrag*)&sm.A[(2 + m) * 1024 + lane * 8];
            bfrag a1 = *(const bfrag*)&sm.A[(2 + m) * 1024 + 512 + lane * 8];
            f4 ka = {kbv, kbv, kbv, kbv};
            ka = __builtin_amdgcn_mfma_f32_16x16x32_bf16(a0, kB0, ka, 0, 0, 0);
            ka = __builtin_amdgcn_mfma_f32_16x16x32_bf16(a1, kB1, ka, 0, 0, 0);
            f4 va = {vbv, vbv, vbv, vbv};
            va = __builtin_amdgcn_mfma_f32_16x16x32_bf16(a0, vB0, va, 0, 0, 0);
            va = __builtin_amdgcn_mfma_f32_16x16x32_bf16(a1, vB1, va, 0, 0, 0);

            // q broadcast: pixel p = 4m+lg lives in qacc[m>>2], reg lg, lane (m&3)*16+lq
            int src = ((m & 3) << 4) | lq;
            f4 qa = qacc[m >> 2];
            float t0 = __shfl(qa.x, src), t1 = __shfl(qa.y, src);
            float t2 = __shfl(qa.z, src), t3 = __shfl(qa.w, src);
            float qv = (lg == 0) ? t0 : (lg == 1) ? t1 : (lg == 2) ? t2 : t3;
            qv *= 0.25f; // HEAD_DIM^-0.5

            float s0 = qv * ka.x, s1 = qv * ka.y, s2 = qv * ka.z, s3 = qv * ka.w;
#pragma unroll
            for (int msk = 1; msk < 16; msk <<= 1) {
                s0 += __shfl_xor(s0, msk);
                s1 += __shfl_xor(s1, msk);
                s2 += __shfl_xor(s2, msk);
                s3 += __shfl_xor(s3, msk);
            }
            float mx = fmaxf(fmaxf(s0, s1), fmaxf(s2, s3));
            float e0 = __expf(s0 - mx), e1 = __expf(s1 - mx);
            float e2 = __expf(s2 - mx), e3 = __expf(s3 - mx);
            float rden = 1.0f / (e0 + e1 + e2 + e3);
            float o = (e0 * va.x + e1 * va.y + e2 * va.z + e3 * va.w) * rden;
            sm.outt[((wid << 4) + lq) * 33 + (m << 2) + lg] = o;
        }
        __syncthreads();
        // flush 64 channels (this hh pass) as full 128B lines
        if (tid < 128) {
            int l = tid >> 1, half = tid & 1;
            int gch = (((l >> 4) << 1) + hh) * 16 + (l & 15);
            const float* sp = &sm.outt[l * 33 + half * 16];
            float4* dst = (float4*)(out + (size_t)(n * 128 + gch) * HW_ + rem0 + half * 16);
#pragma unroll
            for (int i2 = 0; i2 < 4; ++i2)
                dst[i2] = make_float4(sp[4 * i2], sp[4 * i2 + 1], sp[4 * i2 + 2], sp[4 * i2 + 3]);
        }
        __syncthreads();
    }
}

extern "C" void kernel_launch(void* const* d_in, const int* in_sizes, int n_in,
                              void* d_out, int out_size, void* d_ws, size_t ws_size,
                              hipStream_t stream) {
    unsigned short* wsb = (unsigned short*)d_ws;
    float* offs_g = (float*)d_ws + 12288; // after 48 KB of weight frags
    hipLaunchKernelGGL(prep_wfrag, dim3(96), dim3(256), 0, stream,
                       (const float*)d_in[4], (const float*)d_in[6],
                       (const float*)d_in[8], wsb);
    hipLaunchKernelGGL(conv_kernel, dim3(NPIX_ / 64), dim3(256), 0, stream,
                       (const float*)d_in[0], (const float*)d_in[1],
                       (const float*)d_in[2], (const float*)d_in[3], offs_g);
    hipLaunchKernelGGL(fused_kernel, dim3(NPIX_ / 32), dim3(256), 0, stream,
                       (const float*)d_in[0], (const float*)d_in[1],
                       (const float*)d_in[5], (const float*)d_in[7],
                       (const float*)d_in[9], wsb, offs_g,
                       (float*)d_out);
}

// Round 4
// 154.079 us; speedup vs baseline: 1.7102x; 1.1817x over previous
//
#include <hip/hip_runtime.h>
#include <hip/hip_bf16.h>

#define HW_ 36864
#define W_ 192
#define H_ 192
#define NPIX_ 73728
#define TWO_PI_F 6.283185307179586f

typedef __attribute__((ext_vector_type(8))) short bfrag;
typedef __attribute__((ext_vector_type(4))) float f4;

__device__ __constant__ float DT_G[12] = {
    1.0f, 2.154434690031884f, 4.641588833612779f, 10.0f,
    21.54434690031884f, 46.41588833612779f, 100.0f, 215.4434690031884f,
    464.1588833612779f, 1000.0f, 2154.434690031884f, 4641.588833612779f};

__device__ __forceinline__ unsigned short f2bf(float f) {
    __hip_bfloat16 h = __float2bfloat16(f);
    unsigned short u;
    __builtin_memcpy(&u, &h, 2);
    return u;
}

// A-frag storage index (u16 units) for (row m in tile, k in 0..63)
__device__ __forceinline__ int a_idx(int tile, int m, int k) {
    return tile * 1024 + ((k >> 5) << 9) + (m << 3) + (((k >> 3) & 3) << 7) + (k & 7);
}

// ---- prep kernel: build frag-ordered bf16 weights once into workspace ----
// layout: [mat 0..2][h 0..7][ks 0..1][lane 0..63][j 0..7] bf16  (24576 elems, 48 KB)
__global__ void prep_wfrag(const float* __restrict__ qw, const float* __restrict__ kw,
                           const float* __restrict__ vw, unsigned short* __restrict__ wsb) {
    int idx = blockIdx.x * 256 + threadIdx.x;
    if (idx >= 24576) return;
    int j = idx & 7;
    int lane = (idx >> 3) & 63;
    int ks = (idx >> 9) & 1;
    int h = (idx >> 10) & 7;
    int mat = idx >> 13;
    const float* w = (mat == 0) ? qw : (mat == 1) ? kw : vw;
    int k = ks * 32 + ((lane >> 4) << 3) + j;
    int n = (h << 4) + (lane & 15);
    float f = (k < 48) ? w[k * 128 + n] : 0.0f;
    wsb[idx] = f2bf(f);
}

// ---- conv kernel: 3x3 conv -> per-pixel offset ----
// Explicit 54-load register batching (MLP fix); FMA order bit-identical to the
// serial version: accA = channels [0..11] of the wave's 24, accB = [12..23],
// taps 0..8 within each channel.
__global__ __launch_bounds__(256, 4) void conv_kernel(
    const float* __restrict__ y, const float* __restrict__ x,
    const float* __restrict__ cw, const float* __restrict__ cb,
    float* __restrict__ offs_g) {
    __shared__ float part[8][64];
    int tid = threadIdx.x;
    int bid = blockIdx.x;
    int b = (bid & 7) * 144 + (bid >> 3); // bijective XCD swizzle (1152 = 8*144)
    int pix0 = b * 64;
    int n = pix0 / HW_;
    int rem = pix0 - n * HW_;
    int row0 = rem / W_;
    int col0 = rem - row0 * W_; // 64 px share one row (W_%64==0)
    int lane = tid & 63, w = tid >> 6;
    int col = col0 + lane;

    float m_lf = (col > 0) ? 1.f : 0.f, m_rt = (col < W_ - 1) ? 1.f : 0.f;
    float m_up = (row0 > 0) ? 1.f : 0.f, m_dn = (row0 < H_ - 1) ? 1.f : 0.f;
    int c_lf = col - (col > 0 ? 1 : 0);
    int c_rt = col + (col < W_ - 1 ? 1 : 0);
    int r_up = row0 - (row0 > 0 ? 1 : 0);
    int r_dn = row0 + (row0 < H_ - 1 ? 1 : 0);
    float k0 = m_up * m_lf, k1 = m_up, k2 = m_up * m_rt;
    float k3 = m_lf, k5 = m_rt;
    float k6 = m_dn * m_lf, k7 = m_dn, k8 = m_dn * m_rt;

    float accA = 0.f, accB = 0.f;
#pragma unroll
    for (int g = 0; g < 4; ++g) {
        float buf[54]; // 6 channels x 9 taps, all loads issued before any FMA
#pragma unroll
        for (int cc = 0; cc < 6; ++cc) {
            int ic = w * 24 + g * 6 + cc;
            const float* src = (ic < 48) ? y : x;
            int c = (ic < 48) ? ic : ic - 48;
            const float* b0 = src + (size_t)(n * 48 + c) * HW_;
            const float* pu = b0 + (size_t)r_up * W_;
            const float* pm = b0 + (size_t)row0 * W_;
            const float* pd = b0 + (size_t)r_dn * W_;
            buf[cc * 9 + 0] = pu[c_lf];
            buf[cc * 9 + 1] = pu[col];
            buf[cc * 9 + 2] = pu[c_rt];
            buf[cc * 9 + 3] = pm[c_lf];
            buf[cc * 9 + 4] = pm[col];
            buf[cc * 9 + 5] = pm[c_rt];
            buf[cc * 9 + 6] = pd[c_lf];
            buf[cc * 9 + 7] = pd[col];
            buf[cc * 9 + 8] = pd[c_rt];
        }
        float& acc = (g < 2) ? accA : accB;
#pragma unroll
        for (int cc = 0; cc < 6; ++cc) {
            int ic = w * 24 + g * 6 + cc;
            const float* wp = cw + ic * 9;
            acc += buf[cc * 9 + 0] * (wp[0] * k0);
            acc += buf[cc * 9 + 1] * (wp[1] * k1);
            acc += buf[cc * 9 + 2] * (wp[2] * k2);
            acc += buf[cc * 9 + 3] * (wp[3] * k3);
            acc += buf[cc * 9 + 4] * wp[4];
            acc += buf[cc * 9 + 5] * (wp[5] * k5);
            acc += buf[cc * 9 + 6] * (wp[6] * k6);
            acc += buf[cc * 9 + 7] * (wp[7] * k7);
            acc += buf[cc * 9 + 8] * (wp[8] * k8);
        }
    }
    part[2 * w][lane] = accA;
    part[2 * w + 1][lane] = accB;
    __syncthreads();
    if (tid < 64) {
        float a = part[0][tid];
#pragma unroll
        for (int s = 1; s < 8; ++s) a += part[s][tid];
        offs_g[pix0 + tid] = (a + cb[0]) * (2.0f / (float)W_);
    }
}

// ---- main kernel: 512 threads, 8 waves, 1 head per wave ----
struct __align__(16) Smem {
    unsigned short A[10 * 1024]; // [0..1]=xin (32 rows), [2..9]=wrp (128 rows)
    float outt[128 * 33];        // out tile [128 ch][32px], pad 33
    float pbl[192];              // window position bias [v][c]
    float offs[32];              // per-pixel offsets
}; // ~37.7 KB -> 4 blocks/CU (LDS), 32 waves = 100% cap

__global__ __launch_bounds__(512, 6) void fused_kernel(
    const float* __restrict__ y, const float* __restrict__ x,
    const float* __restrict__ qb, const float* __restrict__ kb,
    const float* __restrict__ vb, const unsigned short* __restrict__ wsb,
    const float* __restrict__ offs_g, float* __restrict__ out) {
    __shared__ Smem sm;
    int tid = threadIdx.x;
    int bid = blockIdx.x;
    int b = (bid & 7) * 288 + (bid >> 3); // bijective XCD swizzle (2304 = 8*288)
    int pix0 = b * 32;
    int n = pix0 / HW_;
    int rem0 = pix0 - n * HW_;
    int row0 = rem0 / W_;
    int col0 = rem0 - row0 * W_;

    // xin global prefetch (addresses independent of offs) — 3 ch per thread
    float xv[3];
    {
        int p = tid & 31, c0 = tid >> 5; // c0 in 0..15
        const float* xb = x + (size_t)(n * 48) * HW_ + rem0 + p;
#pragma unroll
        for (int k2 = 0; k2 < 3; ++k2) xv[k2] = xb[(size_t)(c0 + 16 * k2) * HW_];
    }

    // ---- phase 1: offs load, position bias, zero A k-pad ----
    if (tid < 32) sm.offs[tid] = offs_g[pix0 + tid];
    if (tid < 192) {
        int v = tid / 48, c = tid - (tid / 48) * 48;
        int iy = v >> 1, ix = v & 1;
        int cc = (c < 24) ? c : c - 24;
        int sel = (c < 24) ? iy : ix;
        float e = sel ? (TWO_PI_F / (1.0f + 1e-6f)) : 0.0f;
        int j = cc >> 1;
        float arg = e / DT_G[j];
        sm.pbl[v * 48 + c] = (cc & 1) ? __cosf(arg) : __sinf(arg);
    }
    // only k in [48,64) slots need zeroing (B is zero there)
    for (int i = tid; i < 1280; i += 512) {
        int t = i >> 7;
        ((unsigned int*)sm.A)[t * 512 + 384 + (i & 127)] = 0u;
    }
    __syncthreads();

    // ---- phase 2: stage A operands ----
    // xin: 32px x 48c, 3 channels per thread
    {
        int p = tid & 31, c0 = tid >> 5;
        float o = sm.offs[p];
        float gx = (float)(col0 + p) + o;
        float fr = gx - floorf(gx);
        float t1 = fr / (2.0f + 1e-6f);
#pragma unroll
        for (int k2 = 0; k2 < 3; ++k2) {
            int c = c0 + 16 * k2;
            float pe;
            if (c < 24) {
                pe = (c & 1) ? 1.0f : 0.0f; // frac_y == 0
            } else {
                int cc = c - 24;
                float arg = (t1 * TWO_PI_F) / DT_G[cc >> 1];
                pe = (cc & 1) ? __cosf(arg) : __sinf(arg);
            }
            sm.A[a_idx(p >> 4, p & 15, c)] = f2bf(xv[k2] + pe);
        }
    }
    // wrp: 128 rows (px*4+v) x 48c — 12 channels per thread, batched loads
    {
        int r = tid & 127, cH = tid >> 7; // cH in 0..3
        int p = r >> 2, v = r & 3;
        float o = sm.offs[p];
        float gx = (float)(col0 + p) + o;
        float fx = floorf(gx);
        int dy = v >> 1, dx = v & 1;
        int rr = (int)fminf(fmaxf((float)(row0 + dy), 0.0f), 191.0f);
        int ccx = (int)fminf(fmaxf(fx + (float)dx, 0.0f), 191.0f);
        const float* yb = y + (size_t)(n * 48 + cH) * HW_ + rr * W_ + ccx;
        float yv[12];
#pragma unroll
        for (int k2 = 0; k2 < 12; ++k2) yv[k2] = yb[(size_t)(4 * k2) * HW_];
        int t = 2 + (r >> 4), m = r & 15;
#pragma unroll
        for (int k2 = 0; k2 < 12; ++k2) {
            int c = cH + 4 * k2;
            sm.A[a_idx(t, m, c)] = f2bf(yv[k2] + sm.pbl[v * 48 + c]);
        }
    }
    __syncthreads();

    // ---- phase 3: MFMA projections + register attention, 1 head per wave ----
    int lane = tid & 63, h = tid >> 6;
    int lq = lane & 15, lg = lane >> 4;
    float qbv = qb[(h << 4) + lq];
    float kbv = kb[(h << 4) + lq];
    float vbv = vb[(h << 4) + lq];

    const int hb = (h << 1) * 64 + lane;
    bfrag qB0 = *(const bfrag*)&wsb[(0 * 1024 + hb) * 8];
    bfrag qB1 = *(const bfrag*)&wsb[(0 * 1024 + hb + 64) * 8];
    bfrag kB0 = *(const bfrag*)&wsb[(1 * 1024 + hb) * 8];
    bfrag kB1 = *(const bfrag*)&wsb[(1 * 1024 + hb + 64) * 8];
    bfrag vB0 = *(const bfrag*)&wsb[(2 * 1024 + hb) * 8];
    bfrag vB1 = *(const bfrag*)&wsb[(2 * 1024 + hb + 64) * 8];

    f4 qacc[2];
#pragma unroll
    for (int t = 0; t < 2; ++t) {
        bfrag a0 = *(const bfrag*)&sm.A[t * 1024 + lane * 8];
        bfrag a1 = *(const bfrag*)&sm.A[t * 1024 + 512 + lane * 8];
        f4 a = {qbv, qbv, qbv, qbv};
        a = __builtin_amdgcn_mfma_f32_16x16x32_bf16(a0, qB0, a, 0, 0, 0);
        a = __builtin_amdgcn_mfma_f32_16x16x32_bf16(a1, qB1, a, 0, 0, 0);
        qacc[t] = a;
    }

#pragma unroll
    for (int m = 0; m < 8; ++m) {
        bfrag a0 = *(const bfrag*)&sm.A[(2 + m) * 1024 + lane * 8];
        bfrag a1 = *(const bfrag*)&sm.A[(2 + m) * 1024 + 512 + lane * 8];
        f4 ka = {kbv, kbv, kbv, kbv};
        ka = __builtin_amdgcn_mfma_f32_16x16x32_bf16(a0, kB0, ka, 0, 0, 0);
        ka = __builtin_amdgcn_mfma_f32_16x16x32_bf16(a1, kB1, ka, 0, 0, 0);
        f4 va = {vbv, vbv, vbv, vbv};
        va = __builtin_amdgcn_mfma_f32_16x16x32_bf16(a0, vB0, va, 0, 0, 0);
        va = __builtin_amdgcn_mfma_f32_16x16x32_bf16(a1, vB1, va, 0, 0, 0);

        // q broadcast: pixel p = 4m+lg lives in qacc[m>>2], reg lg, lane (m&3)*16+lq
        int src = ((m & 3) << 4) | lq;
        f4 qa = qacc[m >> 2];
        float t0 = __shfl(qa.x, src), t1 = __shfl(qa.y, src);
        float t2 = __shfl(qa.z, src), t3 = __shfl(qa.w, src);
        float qv = (lg == 0) ? t0 : (lg == 1) ? t1 : (lg == 2) ? t2 : t3;
        qv *= 0.25f; // HEAD_DIM^-0.5

        float s0 = qv * ka.x, s1 = qv * ka.y, s2 = qv * ka.z, s3 = qv * ka.w;
#pragma unroll
        for (int msk = 1; msk < 16; msk <<= 1) {
            s0 += __shfl_xor(s0, msk);
            s1 += __shfl_xor(s1, msk);
            s2 += __shfl_xor(s2, msk);
            s3 += __shfl_xor(s3, msk);
        }
        float mx = fmaxf(fmaxf(s0, s1), fmaxf(s2, s3));
        float e0 = __expf(s0 - mx), e1 = __expf(s1 - mx);
        float e2 = __expf(s2 - mx), e3 = __expf(s3 - mx);
        float rden = 1.0f / (e0 + e1 + e2 + e3);
        float o = (e0 * va.x + e1 * va.y + e2 * va.z + e3 * va.w) * rden;
        sm.outt[((h << 4) + lq) * 33 + (m << 2) + lg] = o;
    }
    __syncthreads();

    // ---- phase 4: coalesced flush, all 512 threads ----
    {
        int ch = tid >> 2, q4 = tid & 3;
        const float* sp = &sm.outt[ch * 33 + q4 * 8];
        float4* dst = (float4*)(out + (size_t)(n * 128 + ch) * HW_ + rem0 + q4 * 8);
        dst[0] = make_float4(sp[0], sp[1], sp[2], sp[3]);
        dst[1] = make_float4(sp[4], sp[5], sp[6], sp[7]);
    }
}

extern "C" void kernel_launch(void* const* d_in, const int* in_sizes, int n_in,
                              void* d_out, int out_size, void* d_ws, size_t ws_size,
                              hipStream_t stream) {
    unsigned short* wsb = (unsigned short*)d_ws;
    float* offs_g = (float*)d_ws + 12288; // after 48 KB of weight frags
    hipLaunchKernelGGL(prep_wfrag, dim3(96), dim3(256), 0, stream,
                       (const float*)d_in[4], (const float*)d_in[6],
                       (const float*)d_in[8], wsb);
    hipLaunchKernelGGL(conv_kernel, dim3(NPIX_ / 64), dim3(256), 0, stream,
                       (const float*)d_in[0], (const float*)d_in[1],
                       (const float*)d_in[2], (const float*)d_in[3], offs_g);
    hipLaunchKernelGGL(fused_kernel, dim3(NPIX_ / 32), dim3(512), 0, stream,
                       (const float*)d_in[0], (const float*)d_in[1],
                       (const float*)d_in[5], (const float*)d_in[7],
                       (const float*)d_in[9], wsb, offs_g,
                       (float*)d_out);
}

// Round 5
// 135.572 us; speedup vs baseline: 1.9437x; 1.1365x over previous
//
#include <hip/hip_runtime.h>
#include <hip/hip_bf16.h>

#define HW_ 36864
#define W_ 192
#define H_ 192
#define NPIX_ 73728
#define TWO_PI_F 6.283185307179586f

typedef __attribute__((ext_vector_type(8))) short bfrag;
typedef __attribute__((ext_vector_type(4))) float f4;

__device__ __constant__ float DT_G[12] = {
    1.0f, 2.154434690031884f, 4.641588833612779f, 10.0f,
    21.54434690031884f, 46.41588833612779f, 100.0f, 215.4434690031884f,
    464.1588833612779f, 1000.0f, 2154.434690031884f, 4641.588833612779f};

__device__ __forceinline__ unsigned short f2bf(float f) {
    __hip_bfloat16 h = __float2bfloat16(f);
    unsigned short u;
    __builtin_memcpy(&u, &h, 2);
    return u;
}

// A-frag storage index (u16 units) for (row m in tile, k in 0..63).
// k-octets (8 consecutive k, 8-aligned) are contiguous 16B -> b128-writable.
__device__ __forceinline__ int a_idx(int tile, int m, int k) {
    return tile * 1024 + ((k >> 5) << 9) + (m << 3) + (((k >> 3) & 3) << 7) + (k & 7);
}

// 4x4 transpose of a 16-row tile index (involution). Staging xin rows with this
// permutation makes the Q-MFMA output land in-lane for the attention loop:
// lane(lq,lg) reg j = q[16t + 4j + lg][lq]  ->  qv for m is qacc[m>>2] reg (m&3).
__device__ __forceinline__ int rsw(int r) { return ((r & 3) << 2) | (r >> 2); }

// 16-lane sum via VALU DPP row_ror (no LDS pipe). Tree ror 8,4,2,1: after the
// ror:8 step the row is 8-periodic, so ror:4 pairs i with i^4, etc. All lanes
// end with the identical (bitwise) sum.
__device__ __forceinline__ float red16(float v) {
    int t;
    t = __builtin_amdgcn_update_dpp(0, __float_as_int(v), 0x128, 0xF, 0xF, true);
    v += __int_as_float(t);
    t = __builtin_amdgcn_update_dpp(0, __float_as_int(v), 0x124, 0xF, 0xF, true);
    v += __int_as_float(t);
    t = __builtin_amdgcn_update_dpp(0, __float_as_int(v), 0x122, 0xF, 0xF, true);
    v += __int_as_float(t);
    t = __builtin_amdgcn_update_dpp(0, __float_as_int(v), 0x121, 0xF, 0xF, true);
    v += __int_as_float(t);
    return v;
}

// ---- prep kernel: build frag-ordered bf16 weights once into workspace ----
// layout: [mat 0..2][h 0..7][ks 0..1][lane 0..63][j 0..7] bf16  (24576 elems, 48 KB)
__global__ void prep_wfrag(const float* __restrict__ qw, const float* __restrict__ kw,
                           const float* __restrict__ vw, unsigned short* __restrict__ wsb) {
    int idx = blockIdx.x * 256 + threadIdx.x;
    if (idx >= 24576) return;
    int j = idx & 7;
    int lane = (idx >> 3) & 63;
    int ks = (idx >> 9) & 1;
    int h = (idx >> 10) & 7;
    int mat = idx >> 13;
    const float* w = (mat == 0) ? qw : (mat == 1) ? kw : vw;
    int k = ks * 32 + ((lane >> 4) << 3) + j;
    int n = (h << 4) + (lane & 15);
    float f = (k < 48) ? w[k * 128 + n] : 0.0f;
    wsb[idx] = f2bf(f);
}

// ---- merged kernel: conv + staging + MFMA attention, 512 threads ----
struct __align__(16) Smem {
    unsigned short A[10 * 1024]; // [0..1]=xin (32 rows, rsw-permuted), [2..9]=wrp (128 rows)
    float outt[128 * 33];        // out tile [ch][32px], pad 33
    float pbl[192];              // window position bias [v][c]
    float offs[32];              // per-pixel offsets
    float part[8][32];           // conv partial sums (chain q, pixel)
}; // 39296 B

__global__ __launch_bounds__(512, 4) void fused_kernel(
    const float* __restrict__ y, const float* __restrict__ x,
    const float* __restrict__ cw, const float* __restrict__ cb,
    const float* __restrict__ qb, const float* __restrict__ kb,
    const float* __restrict__ vb, const unsigned short* __restrict__ wsb,
    float* __restrict__ out) {
    __shared__ Smem sm;
    int tid = threadIdx.x;
    int bid = blockIdx.x;
    int b = (bid & 7) * 288 + (bid >> 3); // bijective XCD swizzle (2304 = 8*288)
    int pix0 = b * 32;
    int n = pix0 / HW_;
    int rem0 = pix0 - n * HW_;
    int row0 = rem0 / W_;
    int col0 = rem0 - row0 * W_; // 32 px share one image row (W_%32==0)

    // ---- phase 0: waves 0-3 conv (bit-exact chains); waves 4-7 xin prefetch + pbl ----
    float xv8[8];
    if (tid < 256) {
        // conv: thread = (pixel p, chain q); chain q covers channels
        // (q>>1)*24 + (q&1)*12 + [0..12), FMA order identical to prior rounds.
        int p = tid & 31, q = tid >> 5;
        int col = col0 + p;
        float m_lf = (col > 0) ? 1.f : 0.f, m_rt = (col < W_ - 1) ? 1.f : 0.f;
        float m_up = (row0 > 0) ? 1.f : 0.f, m_dn = (row0 < H_ - 1) ? 1.f : 0.f;
        int c_lf = col - (col > 0 ? 1 : 0);
        int c_rt = col + (col < W_ - 1 ? 1 : 0);
        int r_up = row0 - (row0 > 0 ? 1 : 0);
        int r_dn = row0 + (row0 < H_ - 1 ? 1 : 0);
        float k0 = m_up * m_lf, k1 = m_up, k2 = m_up * m_rt;
        float k3 = m_lf, k5 = m_rt;
        float k6 = m_dn * m_lf, k7 = m_dn, k8 = m_dn * m_rt;
        int icbase = (q >> 1) * 24 + (q & 1) * 12;
        float acc = 0.f;
#pragma unroll
        for (int g2 = 0; g2 < 4; ++g2) { // 4 batches of 3 ch x 9 taps (27 loads in flight)
            float buf[27];
#pragma unroll
            for (int cc = 0; cc < 3; ++cc) {
                int ic = icbase + g2 * 3 + cc;
                const float* src = (ic < 48) ? y : x;
                int c = (ic < 48) ? ic : ic - 48;
                const float* b0p = src + (size_t)(n * 48 + c) * HW_;
                const float* pu = b0p + (size_t)r_up * W_;
                const float* pm = b0p + (size_t)row0 * W_;
                const float* pd = b0p + (size_t)r_dn * W_;
                buf[cc * 9 + 0] = pu[c_lf];
                buf[cc * 9 + 1] = pu[col];
                buf[cc * 9 + 2] = pu[c_rt];
                buf[cc * 9 + 3] = pm[c_lf];
                buf[cc * 9 + 4] = pm[col];
                buf[cc * 9 + 5] = pm[c_rt];
                buf[cc * 9 + 6] = pd[c_lf];
                buf[cc * 9 + 7] = pd[col];
                buf[cc * 9 + 8] = pd[c_rt];
            }
#pragma unroll
            for (int cc = 0; cc < 3; ++cc) {
                int ic = icbase + g2 * 3 + cc;
                const float* wp = cw + ic * 9;
                acc += buf[cc * 9 + 0] * (wp[0] * k0);
                acc += buf[cc * 9 + 1] * (wp[1] * k1);
                acc += buf[cc * 9 + 2] * (wp[2] * k2);
                acc += buf[cc * 9 + 3] * (wp[3] * k3);
                acc += buf[cc * 9 + 4] * wp[4];
                acc += buf[cc * 9 + 5] * (wp[5] * k5);
                acc += buf[cc * 9 + 6] * (wp[6] * k6);
                acc += buf[cc * 9 + 7] * (wp[7] * k7);
                acc += buf[cc * 9 + 8] * (wp[8] * k8);
            }
        }
        sm.part[q][p] = acc;
    } else {
        int e = tid - 256, p = e & 31, oct = e >> 5; // oct 0..7
        if (oct < 6) {
            const float* xb = x + (size_t)(n * 48 + oct * 8) * HW_ + rem0 + p;
#pragma unroll
            for (int j = 0; j < 8; ++j) xv8[j] = xb[(size_t)j * HW_];
        }
        if (e < 192) { // window position bias
            int v = e / 48, c = e - (e / 48) * 48;
            int iy = v >> 1, ix = v & 1;
            int cc = (c < 24) ? c : c - 24;
            int sel = (c < 24) ? iy : ix;
            float ee = sel ? (TWO_PI_F / (1.0f + 1e-6f)) : 0.0f;
            float arg = ee / DT_G[cc >> 1];
            sm.pbl[v * 48 + c] = (cc & 1) ? __cosf(arg) : __sinf(arg);
        }
    }
    __syncthreads();
    if (tid < 32) {
        float a = sm.part[0][tid];
#pragma unroll
        for (int s = 1; s < 8; ++s) a += sm.part[s][tid];
        sm.offs[tid] = (a + cb[0]) * (2.0f / (float)W_);
    }
    __syncthreads();

    // ---- phase 2: staging (b128 LDS writes) ----
    // wrp gather: tid<384, thread = (row r, oct): octets {oct, oct+3} = 16 ch
    float yv[16];
    int r_w = tid & 127, oct_w = tid >> 7, t_w = 0, m_w = 0, v_w = 0;
    bool do_wrp = tid < 384;
    if (do_wrp) {
        int p = r_w >> 2;
        v_w = r_w & 3;
        float o = sm.offs[p];
        float gx = (float)(col0 + p) + o;
        float fx = floorf(gx);
        int dy = v_w >> 1, dx = v_w & 1;
        int rr = (int)fminf(fmaxf((float)(row0 + dy), 0.0f), 191.0f);
        int ccx = (int)fminf(fmaxf(fx + (float)dx, 0.0f), 191.0f);
        const float* yb = y + (size_t)(n * 48) * HW_ + (size_t)rr * W_ + ccx;
#pragma unroll
        for (int j = 0; j < 8; ++j) yv[j] = yb[(size_t)(oct_w * 8 + j) * HW_];
#pragma unroll
        for (int j = 0; j < 8; ++j) yv[8 + j] = yb[(size_t)((oct_w + 3) * 8 + j) * HW_];
        t_w = 2 + (r_w >> 4);
        m_w = r_w & 15;
    }
    if (tid >= 256) {
        // xin: one b128 per thread; rows rsw-permuted; octets 6,7 = zero pad
        int e = tid - 256, p = e & 31, oct = e >> 5;
        bfrag w0;
        if (oct < 6) {
            float o = sm.offs[p];
            float gx = (float)(col0 + p) + o;
            float fr = gx - floorf(gx);
            float t1 = fr / (2.0f + 1e-6f);
#pragma unroll
            for (int j = 0; j < 8; ++j) {
                float pe;
                if (oct < 3) {
                    pe = (j & 1) ? 1.0f : 0.0f; // frac_y == 0
                } else {
                    int cc = oct * 8 + j - 24;
                    float arg = (t1 * TWO_PI_F) / DT_G[cc >> 1];
                    pe = (cc & 1) ? __cosf(arg) : __sinf(arg);
                }
                w0[j] = (short)f2bf(xv8[j] + pe);
            }
        } else {
#pragma unroll
            for (int j = 0; j < 8; ++j) w0[j] = 0;
        }
        *(bfrag*)&sm.A[a_idx(p >> 4, rsw(p & 15), oct * 8)] = w0;
    } else {
        // zero wrp pad octets 6,7
        int r = tid & 127, o2 = 6 + (tid >> 7);
        bfrag z;
#pragma unroll
        for (int j = 0; j < 8; ++j) z[j] = 0;
        *(bfrag*)&sm.A[a_idx(2 + (r >> 4), r & 15, o2 * 8)] = z;
    }
    if (do_wrp) {
        bfrag w0, w1;
#pragma unroll
        for (int j = 0; j < 8; ++j)
            w0[j] = (short)f2bf(yv[j] + sm.pbl[v_w * 48 + oct_w * 8 + j]);
#pragma unroll
        for (int j = 0; j < 8; ++j)
            w1[j] = (short)f2bf(yv[8 + j] + sm.pbl[v_w * 48 + (oct_w + 3) * 8 + j]);
        *(bfrag*)&sm.A[a_idx(t_w, m_w, oct_w * 8)] = w0;
        *(bfrag*)&sm.A[a_idx(t_w, m_w, (oct_w + 3) * 8)] = w1;
    }
    __syncthreads();

    // ---- phase 3: MFMA projections + register attention, 1 head per wave ----
    int lane = tid & 63, h = tid >> 6;
    int lq = lane & 15, lg = lane >> 4;
    float qbv = qb[(h << 4) + lq];
    float kbv = kb[(h << 4) + lq];
    float vbv = vb[(h << 4) + lq];

    const int hb = (h << 1) * 64 + lane;
    bfrag qB0 = *(const bfrag*)&wsb[(0 * 1024 + hb) * 8];
    bfrag qB1 = *(const bfrag*)&wsb[(0 * 1024 + hb + 64) * 8];
    bfrag kB0 = *(const bfrag*)&wsb[(1 * 1024 + hb) * 8];
    bfrag kB1 = *(const bfrag*)&wsb[(1 * 1024 + hb + 64) * 8];
    bfrag vB0 = *(const bfrag*)&wsb[(2 * 1024 + hb) * 8];
    bfrag vB1 = *(const bfrag*)&wsb[(2 * 1024 + hb + 64) * 8];

    f4 qacc[2];
#pragma unroll
    for (int t = 0; t < 2; ++t) {
        bfrag a0 = *(const bfrag*)&sm.A[t * 1024 + lane * 8];
        bfrag a1 = *(const bfrag*)&sm.A[t * 1024 + 512 + lane * 8];
        f4 a = {qbv, qbv, qbv, qbv};
        a = __builtin_amdgcn_mfma_f32_16x16x32_bf16(a0, qB0, a, 0, 0, 0);
        a = __builtin_amdgcn_mfma_f32_16x16x32_bf16(a1, qB1, a, 0, 0, 0);
        qacc[t] = a;
    }

#pragma unroll
    for (int m = 0; m < 8; ++m) {
        bfrag a0 = *(const bfrag*)&sm.A[(2 + m) * 1024 + lane * 8];
        bfrag a1 = *(const bfrag*)&sm.A[(2 + m) * 1024 + 512 + lane * 8];
        f4 ka = {kbv, kbv, kbv, kbv};
        ka = __builtin_amdgcn_mfma_f32_16x16x32_bf16(a0, kB0, ka, 0, 0, 0);
        ka = __builtin_amdgcn_mfma_f32_16x16x32_bf16(a1, kB1, ka, 0, 0, 0);
        f4 va = {vbv, vbv, vbv, vbv};
        va = __builtin_amdgcn_mfma_f32_16x16x32_bf16(a0, vB0, va, 0, 0, 0);
        va = __builtin_amdgcn_mfma_f32_16x16x32_bf16(a1, vB1, va, 0, 0, 0);

        // q for pixel 4m+lg, dim lq is IN-LANE thanks to rsw staging: reg (m&3)
        f4 qa = qacc[m >> 2];
        float qv = ((m & 3) == 0) ? qa.x : ((m & 3) == 1) ? qa.y
                 : ((m & 3) == 2) ? qa.z : qa.w;
        qv *= 0.25f; // HEAD_DIM^-0.5

        float s0 = qv * ka.x, s1 = qv * ka.y, s2 = qv * ka.z, s3 = qv * ka.w;
        s0 = red16(s0);
        s1 = red16(s1);
        s2 = red16(s2);
        s3 = red16(s3);
        float mx = fmaxf(fmaxf(s0, s1), fmaxf(s2, s3));
        float e0 = __expf(s0 - mx), e1 = __expf(s1 - mx);
        float e2 = __expf(s2 - mx), e3 = __expf(s3 - mx);
        float rden = 1.0f / (e0 + e1 + e2 + e3);
        float o = (e0 * va.x + e1 * va.y + e2 * va.z + e3 * va.w) * rden;
        sm.outt[((h << 4) + lq) * 33 + (m << 2) + lg] = o;
    }
    __syncthreads();

    // ---- phase 4: coalesced flush, all 512 threads ----
    {
        int ch = tid >> 2, q4 = tid & 3;
        const float* sp = &sm.outt[ch * 33 + q4 * 8];
        float4* dst = (float4*)(out + (size_t)(n * 128 + ch) * HW_ + rem0 + q4 * 8);
        dst[0] = make_float4(sp[0], sp[1], sp[2], sp[3]);
        dst[1] = make_float4(sp[4], sp[5], sp[6], sp[7]);
    }
}

extern "C" void kernel_launch(void* const* d_in, const int* in_sizes, int n_in,
                              void* d_out, int out_size, void* d_ws, size_t ws_size,
                              hipStream_t stream) {
    unsigned short* wsb = (unsigned short*)d_ws;
    hipLaunchKernelGGL(prep_wfrag, dim3(96), dim3(256), 0, stream,
                       (const float*)d_in[4], (const float*)d_in[6],
                       (const float*)d_in[8], wsb);
    hipLaunchKernelGGL(fused_kernel, dim3(NPIX_ / 32), dim3(512), 0, stream,
                       (const float*)d_in[0], (const float*)d_in[1],
                       (const float*)d_in[2], (const float*)d_in[3],
                       (const float*)d_in[5], (const float*)d_in[7],
                       (const float*)d_in[9], wsb,
                       (float*)d_out);
}